// Round 6
// baseline (722.163 us; speedup 1.0000x reference)
//
#include <hip/hip_runtime.h>
#include <hip/hip_bf16.h>
#include <cstdint>
#include <cstddef>

// Problem constants (B=16, S=1024, D=1024); inputs f32, output f32 (verified r4)
#define S_LEN   1024
#define D_DIM   1024
#define QK_DIM  128
#define EXP_DIM 2048
#define H_HEADS 8
#define DH_Q    16
#define DH_V    128
#define M_ROWS  16384         // B*S

typedef __bf16 bf16;
typedef __bf16 b16x4 __attribute__((ext_vector_type(4)));
typedef __bf16 b16x8 __attribute__((ext_vector_type(8)));
typedef float  fx4   __attribute__((ext_vector_type(4)));
typedef float  f32x16 __attribute__((ext_vector_type(16)));

// ---------- async global->LDS (16B per lane) ----------
__device__ __forceinline__ void load_lds16(const bf16* g, bf16* l) {
    __builtin_amdgcn_global_load_lds(
        (const __attribute__((address_space(1))) void*)g,
        (__attribute__((address_space(3))) void*)l, 16, 0, 0);
}

// ---------- convert f32 -> bf16, 4 elements/thread ----------
__global__ __launch_bounds__(256) void convert_kernel(const float* __restrict__ src,
                                                      bf16* __restrict__ dst, int n4) {
    const int i = blockIdx.x * 256 + threadIdx.x;
    if (i >= n4) return;
    const fx4 v = ((const fx4*)src)[i];
    b16x4 o;
#pragma unroll
    for (int k = 0; k < 4; ++k) o[k] = (bf16)v[k];
    ((b16x4*)dst)[i] = o;
}

// ---------- LayerNorm: x (f32) -> xn (bf16) ----------
__global__ __launch_bounds__(256) void ln_kernel(const float* __restrict__ x,
                                                 const float* __restrict__ w,
                                                 bf16* __restrict__ xn) {
    const int row = blockIdx.x;
    const int tid = threadIdx.x;
    const fx4 t = ((const fx4*)x)[(size_t)row * 256 + tid];
    float v[4];
    float s = 0.f, ss = 0.f;
#pragma unroll
    for (int i = 0; i < 4; ++i) { v[i] = t[i]; s += v[i]; ss += v[i] * v[i]; }
#pragma unroll
    for (int off = 32; off >= 1; off >>= 1) {
        s  += __shfl_xor(s,  off);
        ss += __shfl_xor(ss, off);
    }
    __shared__ float ls[4], lss[4];
    const int wave = tid >> 6;
    if ((tid & 63) == 0) { ls[wave] = s; lss[wave] = ss; }
    __syncthreads();
    s  = ls[0]  + ls[1]  + ls[2]  + ls[3];
    ss = lss[0] + lss[1] + lss[2] + lss[3];
    const float mu  = s * (1.f / D_DIM);
    const float var = ss * (1.f / D_DIM) - mu * mu;
    const float r   = rsqrtf(var + 1e-5f);
    const fx4 w4 = ((const fx4*)w)[tid];
    b16x4 o4;
#pragma unroll
    for (int i = 0; i < 4; ++i) o4[i] = (bf16)((v[i] - mu) * r * w4[i]);
    ((b16x4*)(xn + (size_t)row * D_DIM))[tid] = o4;
}

__device__ __forceinline__ float gelu_exact(float x) {
    return 0.5f * x * (1.f + erff(x * 0.70710678118654752f));
}

// ---------- XCD swizzle: each XCD owns a band of M-tiles, N varies fastest ----------
__device__ __forceinline__ void xcd_tiles(int nt, int mt, int& tm, int& tn) {
    const int lin = blockIdx.y * gridDim.x + blockIdx.x;
    if ((mt & 7) == 0) {
        const int xcd = lin & 7, slot = lin >> 3;
        const int mgrp = mt >> 3;
        tm = xcd * mgrp + slot / nt;
        tn = slot % nt;
    } else { tm = blockIdx.y; tn = blockIdx.x; }
}

// ---------- GEMM: acc[M,N] = A[M,K] * W[N,K]^T  (m97-style, 128x128 tile, BK=32) ----------
// EPI==0: C = bf16(acc).   EPI==1: OutF = acc + R (f32 residual, f32 out).
template <int EPI>
__global__ __launch_bounds__(256) void gemm_bt(const bf16* __restrict__ A,
                                               const bf16* __restrict__ W,
                                               const float* __restrict__ R,
                                               bf16* __restrict__ C,
                                               float* __restrict__ OutF,
                                               int M, int N, int K) {
    __shared__ bf16 As[128 * 32];
    __shared__ bf16 Ws[128 * 32];
    const int tid  = threadIdx.x;
    const int wave = tid >> 6, lane = tid & 63;
    int tmi, tni;
    xcd_tiles(gridDim.x, gridDim.y, tmi, tni);
    const int tile_n = tni * 128;
    const int tile_m = tmi * 128;
    const int m_off = (wave >> 1) * 64, n_off = (wave & 1) * 64;

    fx4 acc[4][4] = {};

    const int c0 = wave * 128 + lane;
    const int c1 = c0 + 64;
    const int r0 = c0 >> 2, cc0 = (c0 & 3) * 8;
    const int r1 = c1 >> 2, cc1 = (c1 & 3) * 8;

    const int mrow = lane & 15, quad = lane >> 4;

    for (int k0 = 0; k0 < K; k0 += 32) {
        load_lds16(A + (size_t)(tile_m + r0) * K + k0 + cc0, &As[c0 * 8]);
        load_lds16(A + (size_t)(tile_m + r1) * K + k0 + cc1, &As[c1 * 8]);
        load_lds16(W + (size_t)(tile_n + r0) * K + k0 + cc0, &Ws[c0 * 8]);
        load_lds16(W + (size_t)(tile_n + r1) * K + k0 + cc1, &Ws[c1 * 8]);
        __syncthreads();

        b16x8 af[4], bfr[4];
#pragma unroll
        for (int i = 0; i < 4; ++i) {
            af[i]  = *(const b16x8*)&As[(m_off + i * 16 + mrow) * 32 + quad * 8];
            bfr[i] = *(const b16x8*)&Ws[(n_off + i * 16 + mrow) * 32 + quad * 8];
        }
#pragma unroll
        for (int mi = 0; mi < 4; ++mi)
#pragma unroll
            for (int ni = 0; ni < 4; ++ni)
                acc[mi][ni] = __builtin_amdgcn_mfma_f32_16x16x32_bf16(
                    af[mi], bfr[ni], acc[mi][ni], 0, 0, 0);
        __syncthreads();
    }

    const int lcol = lane & 15, lrow4 = (lane >> 4) * 4;
#pragma unroll
    for (int mi = 0; mi < 4; ++mi)
#pragma unroll
        for (int ni = 0; ni < 4; ++ni)
#pragma unroll
            for (int r = 0; r < 4; ++r) {
                const int gr = tile_m + m_off + mi * 16 + lrow4 + r;
                const int gc = tile_n + n_off + ni * 16 + lcol;
                const size_t idx = (size_t)gr * N + gc;
                if (EPI == 0) C[idx] = (bf16)acc[mi][ni][r];
                else          OutF[idx] = acc[mi][ni][r] + R[idx];
            }
}

// ---------- Fused expand: lin & pre GEMMs share A-stage; geglu in epilogue ----------
// grid dim3(16,128) -> swizzled. Per block: acc_l, acc_p 128x128 each over K=1024.
// Epilogue: g = lin * gelu(pre); col<1024 -> Cat[:, col]; else VH[:, col-1024].
__global__ __launch_bounds__(256) void expand_fused(const bf16* __restrict__ A,
                                                    const bf16* __restrict__ Wl,
                                                    const bf16* __restrict__ Wp,
                                                    bf16* __restrict__ Cat,
                                                    bf16* __restrict__ VH) {
    __shared__ bf16 As[128 * 32];
    __shared__ bf16 Ls[128 * 32];
    __shared__ bf16 Qs[128 * 32];
    const int tid  = threadIdx.x;
    const int wave = tid >> 6, lane = tid & 63;
    int tmi, tni;
    xcd_tiles(16, 128, tmi, tni);
    const int tile_n = tni * 128;
    const int tile_m = tmi * 128;
    const int m_off = (wave >> 1) * 64, n_off = (wave & 1) * 64;

    fx4 acc_l[4][4] = {};
    fx4 acc_p[4][4] = {};

    const int c0 = wave * 128 + lane;
    const int c1 = c0 + 64;
    const int r0 = c0 >> 2, cc0 = (c0 & 3) * 8;
    const int r1 = c1 >> 2, cc1 = (c1 & 3) * 8;

    const int mrow = lane & 15, quad = lane >> 4;

    for (int k0 = 0; k0 < 1024; k0 += 32) {
        load_lds16(A  + (size_t)(tile_m + r0) * 1024 + k0 + cc0, &As[c0 * 8]);
        load_lds16(A  + (size_t)(tile_m + r1) * 1024 + k0 + cc1, &As[c1 * 8]);
        load_lds16(Wl + (size_t)(tile_n + r0) * 1024 + k0 + cc0, &Ls[c0 * 8]);
        load_lds16(Wl + (size_t)(tile_n + r1) * 1024 + k0 + cc1, &Ls[c1 * 8]);
        load_lds16(Wp + (size_t)(tile_n + r0) * 1024 + k0 + cc0, &Qs[c0 * 8]);
        load_lds16(Wp + (size_t)(tile_n + r1) * 1024 + k0 + cc1, &Qs[c1 * 8]);
        __syncthreads();

        b16x8 af[4];
#pragma unroll
        for (int i = 0; i < 4; ++i)
            af[i] = *(const b16x8*)&As[(m_off + i * 16 + mrow) * 32 + quad * 8];
        {
            b16x8 bl[4];
#pragma unroll
            for (int i = 0; i < 4; ++i)
                bl[i] = *(const b16x8*)&Ls[(n_off + i * 16 + mrow) * 32 + quad * 8];
#pragma unroll
            for (int mi = 0; mi < 4; ++mi)
#pragma unroll
                for (int ni = 0; ni < 4; ++ni)
                    acc_l[mi][ni] = __builtin_amdgcn_mfma_f32_16x16x32_bf16(
                        af[mi], bl[ni], acc_l[mi][ni], 0, 0, 0);
        }
        {
            b16x8 bp[4];
#pragma unroll
            for (int i = 0; i < 4; ++i)
                bp[i] = *(const b16x8*)&Qs[(n_off + i * 16 + mrow) * 32 + quad * 8];
#pragma unroll
            for (int mi = 0; mi < 4; ++mi)
#pragma unroll
                for (int ni = 0; ni < 4; ++ni)
                    acc_p[mi][ni] = __builtin_amdgcn_mfma_f32_16x16x32_bf16(
                        af[mi], bp[ni], acc_p[mi][ni], 0, 0, 0);
        }
        __syncthreads();
    }

    const int lcol = lane & 15, lrow4 = (lane >> 4) * 4;
#pragma unroll
    for (int mi = 0; mi < 4; ++mi)
#pragma unroll
        for (int ni = 0; ni < 4; ++ni)
#pragma unroll
            for (int r = 0; r < 4; ++r) {
                const int gr = tile_m + m_off + mi * 16 + lrow4 + r;
                const int gc = tile_n + n_off + ni * 16 + lcol;
                const float g = acc_l[mi][ni][r] * gelu_exact(acc_p[mi][ni][r]);
                if (gc < 1024) Cat[(size_t)gr * EXP_DIM + gc] = (bf16)g;
                else           VH[(size_t)gr * D_DIM + (gc - 1024)] = (bf16)g;
            }
}

// ---------- MFMA flash attention (unchanged from r5 except pbm is f32) ----------
__global__ __launch_bounds__(256) void attn_kernel(const bf16* __restrict__ qk,
                                                   const bf16* __restrict__ vh,
                                                   const float* __restrict__ pbmv,
                                                   const int* __restrict__ fip,
                                                   const int* __restrict__ lip,
                                                   bf16* __restrict__ concatb) {
    const int bh = blockIdx.x;
    const int qt = blockIdx.y;
    const int b = bh >> 3, h = bh & 7;
    const int q0 = qt * 64;
    const int tid  = threadIdx.x;
    const int wave = tid >> 6, lane = tid & 63;
    const int lm = lane & 31, lh = lane >> 5;
    const int qhalf = wave >> 1, sect = wave & 1;

    __shared__ float Ps[64][68];
    __shared__ bf16  Pb[64][72];
    __shared__ bf16  Vt[128][72];
    __shared__ float Mrow[64], Lrow[64], Arow[64];

    const float pm = pbmv[0];
    const float sp = (pm > 20.f) ? pm : log1pf(expf(pm));
    int fi = fip[0], li = lip[0];
    if (fi >= S_LEN) fi = 0;
    if (li >= S_LEN) li = 0;

    const b16x8 qfrag = *(const b16x8*)(qk
        + ((size_t)(b * S_LEN + q0 + qhalf * 32 + lm)) * 256 + h * DH_Q + lh * 8);

    f32x16 accO[2] = {};
    if (tid < 64) { Mrow[tid] = -3e38f; Lrow[tid] = 0.f; }

    const int vkey = tid & 63;
    const int vd   = (tid >> 6) * 32;
    const int srow = wave * 16 + (lane >> 2);
    const int skq  = (lane & 3) * 16;

    const int qmax = q0 + 63;
    for (int k0 = 0; k0 < S_LEN; k0 += 64) {
        const bool any = (k0 <= qmax) || ((qmax >= fi) && (k0 + 63 >= li));
        if (!any) continue;

        __syncthreads();

#pragma unroll
        for (int i = 0; i < 4; ++i) {
            const int d0 = vd + i * 8;
            const b16x8 v8 = *(const b16x8*)(vh
                + ((size_t)(b * S_LEN + k0 + vkey)) * D_DIM + h * DH_V + d0);
#pragma unroll
            for (int j = 0; j < 8; ++j) Vt[d0 + j][vkey] = v8[j];
        }

        {
            const b16x8 kfrag = *(const b16x8*)(qk
                + ((size_t)(b * S_LEN + k0 + sect * 32 + lm)) * 256
                + QK_DIM + h * DH_Q + lh * 8);
            f32x16 z = {};
            const f32x16 S = __builtin_amdgcn_mfma_f32_32x32x16_bf16(qfrag, kfrag, z, 0, 0, 0);
#pragma unroll
            for (int r = 0; r < 16; ++r) {
                const int row = qhalf * 32 + (r & 3) + 8 * (r >> 2) + 4 * lh;
                Ps[row][sect * 32 + lm] = S[r];
            }
        }
        __syncthreads();

        {
            const int rg = q0 + srow;
            float s[16];
#pragma unroll
            for (int i = 0; i < 4; ++i) {
                const fx4 t = *(const fx4*)&Ps[srow][skq + i * 4];
#pragma unroll
                for (int j = 0; j < 4; ++j) {
                    const int jg = k0 + skq + i * 4 + j;
                    const bool act = (jg <= rg) || ((rg >= fi) && (jg >= li));
                    s[i * 4 + j] = act ? (t[j] * 0.25f + sp * (float)(jg - rg)) : -3e38f;
                }
            }
            float mloc = -3e38f;
#pragma unroll
            for (int i = 0; i < 16; ++i) mloc = fmaxf(mloc, s[i]);
            mloc = fmaxf(mloc, __shfl_xor(mloc, 1));
            mloc = fmaxf(mloc, __shfl_xor(mloc, 2));
            const float m_old = Mrow[srow];
            const float m_new = fmaxf(m_old, mloc);
            const float alpha = (m_old <= -1e29f) ? 0.f : expf(m_old - m_new);
            float lsum = 0.f;
            b16x8 p0, p1;
#pragma unroll
            for (int i = 0; i < 16; ++i) {
                const float p = (s[i] <= -1e29f) ? 0.f : expf(s[i] - m_new);
                lsum += p;
                if (i < 8) p0[i] = (bf16)p; else p1[i - 8] = (bf16)p;
            }
            lsum += __shfl_xor(lsum, 1);
            lsum += __shfl_xor(lsum, 2);
            *(b16x8*)&Pb[srow][skq]     = p0;
            *(b16x8*)&Pb[srow][skq + 8] = p1;
            if ((lane & 3) == 0) {
                Mrow[srow] = m_new;
                Lrow[srow] = alpha * Lrow[srow] + lsum;
                Arow[srow] = alpha;
            }
        }
        __syncthreads();

        {
#pragma unroll
            for (int r = 0; r < 16; ++r) {
                const float al = Arow[qhalf * 32 + (r & 3) + 8 * (r >> 2) + 4 * lh];
                accO[0][r] *= al;
                accO[1][r] *= al;
            }
            b16x8 Af[4];
#pragma unroll
            for (int ks = 0; ks < 4; ++ks)
                Af[ks] = *(const b16x8*)&Pb[qhalf * 32 + lm][ks * 16 + lh * 8];
#pragma unroll
            for (int nb = 0; nb < 2; ++nb)
#pragma unroll
                for (int ks = 0; ks < 4; ++ks) {
                    const b16x8 Bf = *(const b16x8*)&Vt[sect * 64 + nb * 32 + lm][ks * 16 + lh * 8];
                    accO[nb] = __builtin_amdgcn_mfma_f32_32x32x16_bf16(Af[ks], Bf, accO[nb], 0, 0, 0);
                }
        }
    }

#pragma unroll
    for (int r = 0; r < 16; ++r) {
        const int row = qhalf * 32 + (r & 3) + 8 * (r >> 2) + 4 * lh;
        const float L = Lrow[row];
        const float inv = (L > 0.f) ? 1.f / L : 0.f;
        const size_t base = ((size_t)(b * S_LEN + q0 + row)) * EXP_DIM
                          + EXP_DIM / 2 + h * DH_V + sect * 64 + lm;
#pragma unroll
        for (int nb = 0; nb < 2; ++nb)
            concatb[base + nb * 32] = (bf16)(accO[nb][r] * inv);
    }
}

// ---------- workspace layout ----------
static constexpr size_t WS0_OFF = 0;                         // concat: 67,108,864
static constexpr size_t QK_OFF  = 67108864;                  // qkb:     8,388,608
static constexpr size_t VH_OFF  = QK_OFF + 8388608;          // vh:     33,554,432
static constexpr size_t EW_OFF  = VH_OFF + 33554432;         // ew bf16: 8,912,896
static constexpr size_t PW_OFF  = EW_OFF + 8912896;          // pw bf16: 4,194,304
static constexpr size_t WS_NEED = PW_OFF + 4194304;          // 122,159,104

extern "C" void kernel_launch(void* const* d_in, const int* in_sizes, int n_in,
                              void* d_out, int out_size, void* d_ws, size_t ws_size,
                              hipStream_t stream) {
    const float* x         = (const float*)d_in[0];
    const float* norm_w    = (const float*)d_in[1];
    const float* expand_w  = (const float*)d_in[2];
    const float* project_w = (const float*)d_in[3];
    const float* pbm       = (const float*)d_in[4];
    const int*   fip       = (const int*)d_in[5];
    const int*   lip       = (const int*)d_in[6];
    float* out = (float*)d_out;

    if (ws_size < WS_NEED) return;

    char* ws = (char*)d_ws;
    bf16* ws0 = (bf16*)(ws + WS0_OFF);
    bf16* qkb = (bf16*)(ws + QK_OFF);
    bf16* vh  = (bf16*)(ws + VH_OFF);
    bf16* ewb = (bf16*)(ws + EW_OFF);
    bf16* pwb = (bf16*)(ws + PW_OFF);
    bf16* xn  = (bf16*)d_out;            // first 32 MB of d_out as xn scratch

    convert_kernel<<<4352, 256, 0, stream>>>(expand_w, ewb, 4456448 / 4);
    convert_kernel<<<2048, 256, 0, stream>>>(project_w, pwb, 2097152 / 4);
    ln_kernel<<<M_ROWS, 256, 0, stream>>>(x, norm_w, xn);

    // q,k: expand rows 0..255
    gemm_bt<0><<<dim3(2, M_ROWS / 128), 256, 0, stream>>>(
        xn, ewb, nullptr, qkb, nullptr, M_ROWS, 256, D_DIM);
    // fused lin+pre+geglu: expand rows 256..2303 (lin), 2304..4351 (pre)
    expand_fused<<<dim3(16, M_ROWS / 128), 256, 0, stream>>>(
        xn, ewb + (size_t)256 * D_DIM, ewb + (size_t)2304 * D_DIM, ws0, vh);
    attn_kernel<<<dim3(128, 16), 256, 0, stream>>>(qkb, vh, pbm, fip, lip, ws0);
    // out(f32) = concat @ project_w^T + x
    gemm_bt<1><<<dim3(8, M_ROWS / 128), 256, 0, stream>>>(
        ws0, pwb, x, nullptr, out, M_ROWS, D_DIM, EXP_DIM);
}

// Round 7
// 630.827 us; speedup vs baseline: 1.1448x; 1.1448x over previous
//
#include <hip/hip_runtime.h>
#include <hip/hip_bf16.h>
#include <cstdint>
#include <cstddef>

// Problem constants (B=16, S=1024, D=1024); inputs f32, output f32 (verified r4)
#define S_LEN   1024
#define D_DIM   1024
#define QK_DIM  128
#define EXP_DIM 2048
#define H_HEADS 8
#define DH_Q    16
#define DH_V    128
#define M_ROWS  16384         // B*S

typedef __bf16 bf16;
typedef __bf16 b16x4 __attribute__((ext_vector_type(4)));
typedef __bf16 b16x8 __attribute__((ext_vector_type(8)));
typedef float  fx4   __attribute__((ext_vector_type(4)));
typedef float  f32x16 __attribute__((ext_vector_type(16)));

// ---------- async global->LDS (16B per lane) ----------
__device__ __forceinline__ void load_lds16(const bf16* g, bf16* l) {
    __builtin_amdgcn_global_load_lds(
        (const __attribute__((address_space(1))) void*)g,
        (__attribute__((address_space(3))) void*)l, 16, 0, 0);
}

// ---------- convert f32 -> bf16, 4 elements/thread ----------
__global__ __launch_bounds__(256) void convert_kernel(const float* __restrict__ src,
                                                      bf16* __restrict__ dst, int n4) {
    const int i = blockIdx.x * 256 + threadIdx.x;
    if (i >= n4) return;
    const fx4 v = ((const fx4*)src)[i];
    b16x4 o;
#pragma unroll
    for (int k = 0; k < 4; ++k) o[k] = (bf16)v[k];
    ((b16x4*)dst)[i] = o;
}

// ---------- LayerNorm: x (f32) -> xn (bf16) ----------
__global__ __launch_bounds__(256) void ln_kernel(const float* __restrict__ x,
                                                 const float* __restrict__ w,
                                                 bf16* __restrict__ xn) {
    const int row = blockIdx.x;
    const int tid = threadIdx.x;
    const fx4 t = ((const fx4*)x)[(size_t)row * 256 + tid];
    float v[4];
    float s = 0.f, ss = 0.f;
#pragma unroll
    for (int i = 0; i < 4; ++i) { v[i] = t[i]; s += v[i]; ss += v[i] * v[i]; }
#pragma unroll
    for (int off = 32; off >= 1; off >>= 1) {
        s  += __shfl_xor(s,  off);
        ss += __shfl_xor(ss, off);
    }
    __shared__ float ls[4], lss[4];
    const int wave = tid >> 6;
    if ((tid & 63) == 0) { ls[wave] = s; lss[wave] = ss; }
    __syncthreads();
    s  = ls[0]  + ls[1]  + ls[2]  + ls[3];
    ss = lss[0] + lss[1] + lss[2] + lss[3];
    const float mu  = s * (1.f / D_DIM);
    const float var = ss * (1.f / D_DIM) - mu * mu;
    const float r   = rsqrtf(var + 1e-5f);
    const fx4 w4 = ((const fx4*)w)[tid];
    b16x4 o4;
#pragma unroll
    for (int i = 0; i < 4; ++i) o4[i] = (bf16)((v[i] - mu) * r * w4[i]);
    ((b16x4*)(xn + (size_t)row * D_DIM))[tid] = o4;
}

__device__ __forceinline__ float gelu_exact(float x) {
    return 0.5f * x * (1.f + erff(x * 0.70710678118654752f));
}

// ---------- clustered XCD tile map ----------
// Assumes linear block id round-robins over 8 XCDs (lin&7). Each XCD owns an
// M-band (MT/8 m-tiles -> A-band 4MB, L2-resident) walked in 4x4 (tm,tn)
// clusters (working set A 1MB + W 1MB << 4MB L2). Fallback: identity.
__device__ __forceinline__ void tile_map(int& tm, int& tn) {
    const int NT = gridDim.x, MT = gridDim.y;
    const int lin = blockIdx.y * NT + blockIdx.x;
    if ((MT & 31) == 0 && (NT & 3) == 0) {
        const int xcd = lin & 7, slot = lin >> 3;
        const int MB  = MT >> 3;
        const int cnc = NT >> 2;                 // clusters per row
        const int c = slot >> 4, w = slot & 15;  // 16 blocks per 4x4 cluster
        const int cm = c / cnc, cn = c - cm * cnc;
        tm = xcd * MB + cm * 4 + (w >> 2);
        tn = cn * 4 + (w & 3);
    } else { tm = blockIdx.y; tn = blockIdx.x; }
}

// ---------- GEMM: acc[M,N] = A[M,K] * W[N,K]^T  (m97-style, 128x128 tile, BK=32) ----------
// EPI==0: C = bf16(acc)
// EPI==1: OutF = acc + R (f32 residual, f32 out)
// EPI==2: fused geglu: l = C[gr*2048+gc]; g = l*gelu(acc);
//         gc<1024 -> C[gr*2048+gc]=g ; else VH[gr*1024+gc-1024]=g
template <int EPI>
__global__ __launch_bounds__(256) void gemm_bt(const bf16* __restrict__ A,
                                               const bf16* __restrict__ W,
                                               const float* __restrict__ R,
                                               bf16* __restrict__ C,
                                               bf16* __restrict__ VH,
                                               float* __restrict__ OutF,
                                               int M, int N, int K) {
    __shared__ bf16 As[128 * 32];
    __shared__ bf16 Ws[128 * 32];
    const int tid  = threadIdx.x;
    const int wave = tid >> 6, lane = tid & 63;
    int tmi, tni;
    tile_map(tmi, tni);
    const int tile_n = tni * 128;
    const int tile_m = tmi * 128;
    const int m_off = (wave >> 1) * 64, n_off = (wave & 1) * 64;

    fx4 acc[4][4] = {};

    const int c0 = wave * 128 + lane;
    const int c1 = c0 + 64;
    const int r0 = c0 >> 2, cc0 = (c0 & 3) * 8;
    const int r1 = c1 >> 2, cc1 = (c1 & 3) * 8;

    const int mrow = lane & 15, quad = lane >> 4;

    for (int k0 = 0; k0 < K; k0 += 32) {
        load_lds16(A + (size_t)(tile_m + r0) * K + k0 + cc0, &As[c0 * 8]);
        load_lds16(A + (size_t)(tile_m + r1) * K + k0 + cc1, &As[c1 * 8]);
        load_lds16(W + (size_t)(tile_n + r0) * K + k0 + cc0, &Ws[c0 * 8]);
        load_lds16(W + (size_t)(tile_n + r1) * K + k0 + cc1, &Ws[c1 * 8]);
        __syncthreads();

        b16x8 af[4], bfr[4];
#pragma unroll
        for (int i = 0; i < 4; ++i) {
            af[i]  = *(const b16x8*)&As[(m_off + i * 16 + mrow) * 32 + quad * 8];
            bfr[i] = *(const b16x8*)&Ws[(n_off + i * 16 + mrow) * 32 + quad * 8];
        }
#pragma unroll
        for (int mi = 0; mi < 4; ++mi)
#pragma unroll
            for (int ni = 0; ni < 4; ++ni)
                acc[mi][ni] = __builtin_amdgcn_mfma_f32_16x16x32_bf16(
                    af[mi], bfr[ni], acc[mi][ni], 0, 0, 0);
        __syncthreads();
    }

    const int lcol = lane & 15, lrow4 = (lane >> 4) * 4;
#pragma unroll
    for (int mi = 0; mi < 4; ++mi)
#pragma unroll
        for (int ni = 0; ni < 4; ++ni)
#pragma unroll
            for (int r = 0; r < 4; ++r) {
                const int gr = tile_m + m_off + mi * 16 + lrow4 + r;
                const int gc = tile_n + n_off + ni * 16 + lcol;
                const float a = acc[mi][ni][r];
                if (EPI == 0) {
                    C[(size_t)gr * N + gc] = (bf16)a;
                } else if (EPI == 1) {
                    const size_t idx = (size_t)gr * N + gc;
                    OutF[idx] = a + R[idx];
                } else {
                    const float l = (float)C[(size_t)gr * 2048 + gc];
                    const float g = l * gelu_exact(a);
                    if (gc < 1024) C[(size_t)gr * 2048 + gc] = (bf16)g;
                    else           VH[(size_t)gr * 1024 + (gc - 1024)] = (bf16)g;
                }
            }
}

// ---------- MFMA flash attention (r5 structure + XCD swizzle on (bh,qt)) ----------
__global__ __launch_bounds__(256) void attn_kernel(const bf16* __restrict__ qk,
                                                   const bf16* __restrict__ vh,
                                                   const float* __restrict__ pbmv,
                                                   const int* __restrict__ fip,
                                                   const int* __restrict__ lip,
                                                   bf16* __restrict__ concatb) {
    // swizzle: all 16 q-tiles of a (b,h) land on one XCD (K/V L2-resident)
    const int lin = blockIdx.y * gridDim.x + blockIdx.x;   // gridDim = (128,16)
    const int xcd = lin & 7, slot = lin >> 3;
    const int bh = xcd * 16 + (slot >> 4);
    const int qt = slot & 15;
    const int b = bh >> 3, h = bh & 7;
    const int q0 = qt * 64;
    const int tid  = threadIdx.x;
    const int wave = tid >> 6, lane = tid & 63;
    const int lm = lane & 31, lh = lane >> 5;
    const int qhalf = wave >> 1, sect = wave & 1;

    __shared__ float Ps[64][68];
    __shared__ bf16  Pb[64][72];
    __shared__ bf16  Vt[128][72];
    __shared__ float Mrow[64], Lrow[64], Arow[64];

    const float pm = pbmv[0];
    const float sp = (pm > 20.f) ? pm : log1pf(expf(pm));
    int fi = fip[0], li = lip[0];
    if (fi >= S_LEN) fi = 0;
    if (li >= S_LEN) li = 0;

    const b16x8 qfrag = *(const b16x8*)(qk
        + ((size_t)(b * S_LEN + q0 + qhalf * 32 + lm)) * 256 + h * DH_Q + lh * 8);

    f32x16 accO[2] = {};
    if (tid < 64) { Mrow[tid] = -3e38f; Lrow[tid] = 0.f; }

    const int vkey = tid & 63;
    const int vd   = (tid >> 6) * 32;
    const int srow = wave * 16 + (lane >> 2);
    const int skq  = (lane & 3) * 16;

    const int qmax = q0 + 63;
    for (int k0 = 0; k0 < S_LEN; k0 += 64) {
        const bool any = (k0 <= qmax) || ((qmax >= fi) && (k0 + 63 >= li));
        if (!any) continue;

        __syncthreads();

#pragma unroll
        for (int i = 0; i < 4; ++i) {
            const int d0 = vd + i * 8;
            const b16x8 v8 = *(const b16x8*)(vh
                + ((size_t)(b * S_LEN + k0 + vkey)) * D_DIM + h * DH_V + d0);
#pragma unroll
            for (int j = 0; j < 8; ++j) Vt[d0 + j][vkey] = v8[j];
        }

        {
            const b16x8 kfrag = *(const b16x8*)(qk
                + ((size_t)(b * S_LEN + k0 + sect * 32 + lm)) * 256
                + QK_DIM + h * DH_Q + lh * 8);
            f32x16 z = {};
            const f32x16 S = __builtin_amdgcn_mfma_f32_32x32x16_bf16(qfrag, kfrag, z, 0, 0, 0);
#pragma unroll
            for (int r = 0; r < 16; ++r) {
                const int row = qhalf * 32 + (r & 3) + 8 * (r >> 2) + 4 * lh;
                Ps[row][sect * 32 + lm] = S[r];
            }
        }
        __syncthreads();

        {
            const int rg = q0 + srow;
            float s[16];
#pragma unroll
            for (int i = 0; i < 4; ++i) {
                const fx4 t = *(const fx4*)&Ps[srow][skq + i * 4];
#pragma unroll
                for (int j = 0; j < 4; ++j) {
                    const int jg = k0 + skq + i * 4 + j;
                    const bool act = (jg <= rg) || ((rg >= fi) && (jg >= li));
                    s[i * 4 + j] = act ? (t[j] * 0.25f + sp * (float)(jg - rg)) : -3e38f;
                }
            }
            float mloc = -3e38f;
#pragma unroll
            for (int i = 0; i < 16; ++i) mloc = fmaxf(mloc, s[i]);
            mloc = fmaxf(mloc, __shfl_xor(mloc, 1));
            mloc = fmaxf(mloc, __shfl_xor(mloc, 2));
            const float m_old = Mrow[srow];
            const float m_new = fmaxf(m_old, mloc);
            const float alpha = (m_old <= -1e29f) ? 0.f : expf(m_old - m_new);
            float lsum = 0.f;
            b16x8 p0, p1;
#pragma unroll
            for (int i = 0; i < 16; ++i) {
                const float p = (s[i] <= -1e29f) ? 0.f : expf(s[i] - m_new);
                lsum += p;
                if (i < 8) p0[i] = (bf16)p; else p1[i - 8] = (bf16)p;
            }
            lsum += __shfl_xor(lsum, 1);
            lsum += __shfl_xor(lsum, 2);
            *(b16x8*)&Pb[srow][skq]     = p0;
            *(b16x8*)&Pb[srow][skq + 8] = p1;
            if ((lane & 3) == 0) {
                Mrow[srow] = m_new;
                Lrow[srow] = alpha * Lrow[srow] + lsum;
                Arow[srow] = alpha;
            }
        }
        __syncthreads();

        {
#pragma unroll
            for (int r = 0; r < 16; ++r) {
                const float al = Arow[qhalf * 32 + (r & 3) + 8 * (r >> 2) + 4 * lh];
                accO[0][r] *= al;
                accO[1][r] *= al;
            }
            b16x8 Af[4];
#pragma unroll
            for (int ks = 0; ks < 4; ++ks)
                Af[ks] = *(const b16x8*)&Pb[qhalf * 32 + lm][ks * 16 + lh * 8];
#pragma unroll
            for (int nb = 0; nb < 2; ++nb)
#pragma unroll
                for (int ks = 0; ks < 4; ++ks) {
                    const b16x8 Bf = *(const b16x8*)&Vt[sect * 64 + nb * 32 + lm][ks * 16 + lh * 8];
                    accO[nb] = __builtin_amdgcn_mfma_f32_32x32x16_bf16(Af[ks], Bf, accO[nb], 0, 0, 0);
                }
        }
    }

#pragma unroll
    for (int r = 0; r < 16; ++r) {
        const int row = qhalf * 32 + (r & 3) + 8 * (r >> 2) + 4 * lh;
        const float L = Lrow[row];
        const float inv = (L > 0.f) ? 1.f / L : 0.f;
        const size_t base = ((size_t)(b * S_LEN + q0 + row)) * EXP_DIM
                          + EXP_DIM / 2 + h * DH_V + sect * 64 + lm;
#pragma unroll
        for (int nb = 0; nb < 2; ++nb)
            concatb[base + nb * 32] = (bf16)(accO[nb][r] * inv);
    }
}

// ---------- workspace layout ----------
static constexpr size_t WS0_OFF = 0;                         // concat: 67,108,864
static constexpr size_t QK_OFF  = 67108864;                  // qkb:     8,388,608
static constexpr size_t VH_OFF  = QK_OFF + 8388608;          // vh:     33,554,432
static constexpr size_t EW_OFF  = VH_OFF + 33554432;         // ew bf16: 8,912,896
static constexpr size_t PW_OFF  = EW_OFF + 8912896;          // pw bf16: 4,194,304
static constexpr size_t WS_NEED = PW_OFF + 4194304;          // 122,159,104

extern "C" void kernel_launch(void* const* d_in, const int* in_sizes, int n_in,
                              void* d_out, int out_size, void* d_ws, size_t ws_size,
                              hipStream_t stream) {
    const float* x         = (const float*)d_in[0];
    const float* norm_w    = (const float*)d_in[1];
    const float* expand_w  = (const float*)d_in[2];
    const float* project_w = (const float*)d_in[3];
    const float* pbm       = (const float*)d_in[4];
    const int*   fip       = (const int*)d_in[5];
    const int*   lip       = (const int*)d_in[6];
    float* out = (float*)d_out;

    if (ws_size < WS_NEED) return;

    char* ws = (char*)d_ws;
    bf16* ws0 = (bf16*)(ws + WS0_OFF);
    bf16* qkb = (bf16*)(ws + QK_OFF);
    bf16* vh  = (bf16*)(ws + VH_OFF);
    bf16* ewb = (bf16*)(ws + EW_OFF);
    bf16* pwb = (bf16*)(ws + PW_OFF);
    bf16* xn  = (bf16*)d_out;            // first 32 MB of d_out as xn scratch

    convert_kernel<<<4352, 256, 0, stream>>>(expand_w, ewb, 4456448 / 4);
    convert_kernel<<<2048, 256, 0, stream>>>(project_w, pwb, 2097152 / 4);
    ln_kernel<<<M_ROWS, 256, 0, stream>>>(x, norm_w, xn);

    // q,k: expand rows 0..255 (NT=2 -> identity tile map)
    gemm_bt<0><<<dim3(2, M_ROWS / 128), 256, 0, stream>>>(
        xn, ewb, nullptr, qkb, nullptr, nullptr, M_ROWS, 256, D_DIM);
    // lin: expand rows 256..2303 -> ws0
    gemm_bt<0><<<dim3(16, M_ROWS / 128), 256, 0, stream>>>(
        xn, ewb + (size_t)256 * D_DIM, nullptr, ws0, nullptr, nullptr, M_ROWS, 2048, D_DIM);
    // pre: expand rows 2304..4351; fused geglu epilogue (reads lin from ws0)
    gemm_bt<2><<<dim3(16, M_ROWS / 128), 256, 0, stream>>>(
        xn, ewb + (size_t)2304 * D_DIM, nullptr, ws0, vh, nullptr, M_ROWS, 2048, D_DIM);
    attn_kernel<<<dim3(128, 16), 256, 0, stream>>>(qkb, vh, pbm, fip, lip, ws0);
    // out(f32) = concat @ project_w^T + x
    gemm_bt<1><<<dim3(8, M_ROWS / 128), 256, 0, stream>>>(
        ws0, pwb, x, nullptr, nullptr, out, M_ROWS, D_DIM, EXP_DIM);
}